// Round 6
// baseline (624.849 us; speedup 1.0000x reference)
//
#include <hip/hip_runtime.h>
#include <hip/hip_bf16.h>

// Problem constants
#define BB 8
#define LL 2048
#define DD 1024
#define HH 16
#define HD 64
#define NMIX 512   // B * HD  (N of the mixing GEMM)

typedef float  f32x4  __attribute__((ext_vector_type(4)));
typedef short  bf16x8 __attribute__((ext_vector_type(8)));
typedef short  s8v    __attribute__((ext_vector_type(8)));
typedef short  s4v    __attribute__((ext_vector_type(4)));

typedef unsigned int u32;
typedef const __attribute__((address_space(1))) u32* gas_ptr;
typedef __attribute__((address_space(3))) u32* las_ptr;

static __device__ __forceinline__ void gload16(const void* g, void* l) {
    // width-16 global->LDS direct copy; LDS dest is wave-uniform base + lane*16
    __builtin_amdgcn_global_load_lds((gas_ptr)g, (las_ptr)l, 16, 0, 0);
}

static __device__ __forceinline__ short f2bf(float f) {
    union { float f; u32 u; } a; a.f = f;
    u32 r = a.u + 0x7FFFu + ((a.u >> 16) & 1u);   // RNE
    return (short)(r >> 16);
}

// ---------------------------------------------------------------------------
// 1) softmax over W*mask rows: W (H*L, L) f32  ->  NW (H*L, L) bf16
// one block per row; row = h*L + i; mask zeroes j > i BEFORE softmax
// ---------------------------------------------------------------------------
__global__ __launch_bounds__(256) void softmax_kernel(const float* __restrict__ W,
                                                      short* __restrict__ NW) {
    const int row = blockIdx.x;
    const int i = row & (LL - 1);
    const float* Wr = W + (size_t)row * LL;
    const int tid = threadIdx.x;
    const int lane = tid & 63, wave = tid >> 6;
    const int jbase = tid * 8;

    float4 a = ((const float4*)Wr)[2 * tid];
    float4 b = ((const float4*)Wr)[2 * tid + 1];
    float v[8] = {a.x, a.y, a.z, a.w, b.x, b.y, b.z, b.w};
#pragma unroll
    for (int j = 0; j < 8; ++j)
        if (jbase + j > i) v[j] = 0.f;

    float mx = v[0];
#pragma unroll
    for (int j = 1; j < 8; ++j) mx = fmaxf(mx, v[j]);
#pragma unroll
    for (int off = 32; off; off >>= 1) mx = fmaxf(mx, __shfl_xor(mx, off));

    __shared__ float redmax[4], redsum[4];
    if (lane == 0) redmax[wave] = mx;
    __syncthreads();
    mx = fmaxf(fmaxf(redmax[0], redmax[1]), fmaxf(redmax[2], redmax[3]));

    float s = 0.f;
#pragma unroll
    for (int j = 0; j < 8; ++j) { v[j] = __expf(v[j] - mx); s += v[j]; }
#pragma unroll
    for (int off = 32; off; off >>= 1) s += __shfl_xor(s, off);
    if (lane == 0) redsum[wave] = s;
    __syncthreads();
    s = redsum[0] + redsum[1] + redsum[2] + redsum[3];
    const float inv = 1.f / s;

    s8v o;
#pragma unroll
    for (int j = 0; j < 8; ++j) o[j] = f2bf(v[j] * inv);
    *(s8v*)(NW + (size_t)row * LL + jbase) = o;
}

// ---------------------------------------------------------------------------
// 2) transpose x (B,L,H,hd) f32 -> xT[h][b*64+d][l] bf16   (K-major B^T)
// grid (L/32, HD/32, H*B), block (32,8)
// ---------------------------------------------------------------------------
__global__ __launch_bounds__(256) void transpose_x(const float* __restrict__ x,
                                                   short* __restrict__ xT) {
    const int hb = blockIdx.z;
    const int h = hb >> 3, b = hb & 7;
    const int l0 = blockIdx.x * 32, d0 = blockIdx.y * 32;
    const int tx = threadIdx.x, ty = threadIdx.y;

    __shared__ float tile[32][33];
#pragma unroll
    for (int j = 0; j < 4; ++j) {
        int l = l0 + ty + 8 * j;
        tile[ty + 8 * j][tx] = x[((size_t)(b * LL + l)) * DD + h * HD + d0 + tx];
    }
    __syncthreads();
#pragma unroll
    for (int j = 0; j < 4; ++j) {
        int n = b * HD + d0 + ty + 8 * j;
        xT[((size_t)(h * NMIX + n)) * LL + l0 + tx] = f2bf(tile[tx][ty + 8 * j]);
    }
}

// ---------------------------------------------------------------------------
// 3) W_proj f32 -> bf16 (layout already B^T: row j, col k)
// ---------------------------------------------------------------------------
__global__ __launch_bounds__(256) void cvt_wproj(const float* __restrict__ Wp,
                                                 short* __restrict__ WpB) {
    const int idx = (blockIdx.x * 256 + threadIdx.x) * 4;
    float4 v = *(const float4*)&Wp[idx];
    s4v o = { f2bf(v.x), f2bf(v.y), f2bf(v.z), f2bf(v.w) };
    *(s4v*)&WpB[idx] = o;
}

// ---------------------------------------------------------------------------
// 4) mixing GEMM (per head): C[i][n] = sum_l NW_h[i][l] * xT_h[n][l]
//    M=2048 N=512 K=2048, m97 structure: 128x128 tile, BK=32, 4 waves
//    epilogue: mixed[(b*2048+i)*1024 + h*64 + d] bf16, where n = b*64+d
// ---------------------------------------------------------------------------
__global__ __launch_bounds__(256) void gemm_mix(const short* __restrict__ NW,
                                                const short* __restrict__ xT,
                                                short* __restrict__ mixed) {
    constexpr int K = LL;
    const int h = blockIdx.z;
    const short* A  = NW + (size_t)h * LL * LL;
    const short* BT = xT + (size_t)h * NMIX * LL;
    const int row0 = blockIdx.x * 128;
    const int col0 = blockIdx.y * 128;

    __shared__ short sA[128 * 32];
    __shared__ short sB[128 * 32];

    const int tid = threadIdx.x;
    const int wave = tid >> 6, lane = tid & 63;
    const int fr = lane & 15, fq = lane >> 4;
    const int wr = wave >> 1, wc = wave & 1;
    const int srow = lane >> 2;          // 0..15 row within 16-row segment
    const int scol = (lane & 3) * 8;     // element offset (8 bf16 = 16 B)

    f32x4 acc[4][4];
#pragma unroll
    for (int m = 0; m < 4; ++m)
#pragma unroll
        for (int n = 0; n < 4; ++n)
            acc[m][n] = f32x4{0.f, 0.f, 0.f, 0.f};

    for (int k0 = 0; k0 < K; k0 += 32) {
#pragma unroll
        for (int q = 0; q < 2; ++q) {
            const int sseg = q * 4 + wave;
            const short* ga = A  + (size_t)(row0 + sseg * 16 + srow) * K + k0 + scol;
            const short* gb = BT + (size_t)(col0 + sseg * 16 + srow) * K + k0 + scol;
            gload16(ga, &sA[sseg * 512]);
            gload16(gb, &sB[sseg * 512]);
        }
        __syncthreads();
        bf16x8 af[4], bfv[4];
#pragma unroll
        for (int m = 0; m < 4; ++m)
            af[m] = *(const bf16x8*)&sA[(wr * 64 + m * 16 + fr) * 32 + fq * 8];
#pragma unroll
        for (int n = 0; n < 4; ++n)
            bfv[n] = *(const bf16x8*)&sB[(wc * 64 + n * 16 + fr) * 32 + fq * 8];
#pragma unroll
        for (int m = 0; m < 4; ++m)
#pragma unroll
            for (int n = 0; n < 4; ++n)
                acc[m][n] = __builtin_amdgcn_mfma_f32_16x16x32_bf16(af[m], bfv[n], acc[m][n], 0, 0, 0);
        __syncthreads();
    }

    const int hbase = h * HD;
#pragma unroll
    for (int m = 0; m < 4; ++m) {
        const int gi = row0 + wr * 64 + m * 16 + fq * 4;   // position i (0..2047)
#pragma unroll
        for (int n = 0; n < 4; ++n) {
            const int ng = col0 + wc * 64 + n * 16 + fr;   // n = b*64+d
            const int bb = ng >> 6, dd = ng & 63;
            const size_t base = ((size_t)(bb * LL) + gi) * DD + hbase + dd;
#pragma unroll
            for (int r = 0; r < 4; ++r)
                mixed[base + (size_t)r * DD] = f2bf(acc[m][n][r]);
        }
    }
}

// ---------------------------------------------------------------------------
// 5) projection GEMM: out[m][j] = sum_k mixed[m][k] * WpB[j][k] + bias[j]
//    M=16384 N=1024 K=1024
// ---------------------------------------------------------------------------
__global__ __launch_bounds__(256) void gemm_proj(const short* __restrict__ Amix,
                                                 const short* __restrict__ WpB,
                                                 const float* __restrict__ bias,
                                                 float* __restrict__ out) {
    constexpr int K = DD;
    const int row0 = blockIdx.x * 128;
    const int col0 = blockIdx.y * 128;

    __shared__ short sA[128 * 32];
    __shared__ short sB[128 * 32];

    const int tid = threadIdx.x;
    const int wave = tid >> 6, lane = tid & 63;
    const int fr = lane & 15, fq = lane >> 4;
    const int wr = wave >> 1, wc = wave & 1;
    const int srow = lane >> 2;
    const int scol = (lane & 3) * 8;

    f32x4 acc[4][4];
#pragma unroll
    for (int m = 0; m < 4; ++m)
#pragma unroll
        for (int n = 0; n < 4; ++n)
            acc[m][n] = f32x4{0.f, 0.f, 0.f, 0.f};

    for (int k0 = 0; k0 < K; k0 += 32) {
#pragma unroll
        for (int q = 0; q < 2; ++q) {
            const int sseg = q * 4 + wave;
            const short* ga = Amix + (size_t)(row0 + sseg * 16 + srow) * K + k0 + scol;
            const short* gb = WpB  + (size_t)(col0 + sseg * 16 + srow) * K + k0 + scol;
            gload16(ga, &sA[sseg * 512]);
            gload16(gb, &sB[sseg * 512]);
        }
        __syncthreads();
        bf16x8 af[4], bfv[4];
#pragma unroll
        for (int m = 0; m < 4; ++m)
            af[m] = *(const bf16x8*)&sA[(wr * 64 + m * 16 + fr) * 32 + fq * 8];
#pragma unroll
        for (int n = 0; n < 4; ++n)
            bfv[n] = *(const bf16x8*)&sB[(wc * 64 + n * 16 + fr) * 32 + fq * 8];
#pragma unroll
        for (int m = 0; m < 4; ++m)
#pragma unroll
            for (int n = 0; n < 4; ++n)
                acc[m][n] = __builtin_amdgcn_mfma_f32_16x16x32_bf16(af[m], bfv[n], acc[m][n], 0, 0, 0);
        __syncthreads();
    }

#pragma unroll
    for (int m = 0; m < 4; ++m) {
        const int grow = row0 + wr * 64 + m * 16 + fq * 4;
#pragma unroll
        for (int n = 0; n < 4; ++n) {
            const int gcol = col0 + wc * 64 + n * 16 + fr;
            const float bj = bias[gcol];
#pragma unroll
            for (int r = 0; r < 4; ++r)
                out[(size_t)(grow + r) * DD + gcol] = acc[m][n][r] + bj;
        }
    }
}

// ---------------------------------------------------------------------------
extern "C" void kernel_launch(void* const* d_in, const int* in_sizes, int n_in,
                              void* d_out, int out_size, void* d_ws, size_t ws_size,
                              hipStream_t stream) {
    const float* x  = (const float*)d_in[0];
    const float* W  = (const float*)d_in[1];
    const float* Wp = (const float*)d_in[2];
    const float* bp = (const float*)d_in[3];
    float* out = (float*)d_out;

    char* ws = (char*)d_ws;
    short* NW    = (short*)(ws);                       // 16*2048*2048*2 = 134217728 B
    short* xT    = (short*)(ws + 134217728);           // 16*512*2048*2  =  33554432 B
    short* mixed = (short*)(ws + 167772160);           // 16384*1024*2   =  33554432 B
    short* WpB   = (short*)(ws + 201326592);           // 1024*1024*2    =   2097152 B
    // total workspace use: 203423744 B (~194 MB)

    softmax_kernel<<<HH * LL, 256, 0, stream>>>(W, NW);
    transpose_x<<<dim3(LL / 32, HD / 32, HH * BB), dim3(32, 8), 0, stream>>>(x, xT);
    cvt_wproj<<<1024, 256, 0, stream>>>(Wp, WpB);
    gemm_mix<<<dim3(LL / 128, NMIX / 128, HH), 256, 0, stream>>>(NW, xT, mixed);
    gemm_proj<<<dim3((BB * LL) / 128, DD / 128), 256, 0, stream>>>(mixed, WpB, bp, out);
}

// Round 7
// 611.381 us; speedup vs baseline: 1.0220x; 1.0220x over previous
//
#include <hip/hip_runtime.h>
#include <hip/hip_bf16.h>

// Problem constants
#define BB 8
#define LL 2048
#define DD 1024
#define HH 16
#define HD 64
#define NMIX 512   // B * HD  (N of the mixing GEMM)

typedef float  f32x4  __attribute__((ext_vector_type(4)));
typedef short  bf16x8 __attribute__((ext_vector_type(8)));
typedef short  s8v    __attribute__((ext_vector_type(8)));
typedef short  s4v    __attribute__((ext_vector_type(4)));

typedef unsigned int u32;
typedef const __attribute__((address_space(1))) u32* gas_ptr;
typedef __attribute__((address_space(3))) u32* las_ptr;

static __device__ __forceinline__ void gload16(const void* g, void* l) {
    // width-16 global->LDS direct copy; LDS dest is wave-uniform base + lane*16
    __builtin_amdgcn_global_load_lds((gas_ptr)g, (las_ptr)l, 16, 0, 0);
}

static __device__ __forceinline__ short f2bf(float f) {
    union { float f; u32 u; } a; a.f = f;
    u32 r = a.u + 0x7FFFu + ((a.u >> 16) & 1u);   // RNE
    return (short)(r >> 16);
}

// ---------------------------------------------------------------------------
// 1) softmax over W*mask rows: W (H*L, L) f32  ->  NW (H*L, L) bf16
// ONE WAVE PER ROW (4 rows/block): no LDS, no barriers, 64-lane shuffle reduce.
// Loads: instr j -> 64 lanes x float4 = 1KB contiguous. Stores: 8B/lane.
// ---------------------------------------------------------------------------
__global__ __launch_bounds__(256) void softmax_kernel(const float* __restrict__ W,
                                                      short* __restrict__ NW) {
    const int wave = threadIdx.x >> 6, lane = threadIdx.x & 63;
    const int row = blockIdx.x * 4 + wave;
    const int i = row & (LL - 1);
    const float4* Wr = (const float4*)(W + (size_t)row * LL);

    float4 c[8];
#pragma unroll
    for (int j = 0; j < 8; ++j) c[j] = Wr[j * 64 + lane];

    float v[32];
#pragma unroll
    for (int j = 0; j < 8; ++j) {
        v[4 * j + 0] = c[j].x; v[4 * j + 1] = c[j].y;
        v[4 * j + 2] = c[j].z; v[4 * j + 3] = c[j].w;
    }
    // causal mask (multiplies weight -> zeros participate in softmax)
#pragma unroll
    for (int j = 0; j < 8; ++j) {
        const int e = (j * 64 + lane) * 4;
#pragma unroll
        for (int k = 0; k < 4; ++k)
            if (e + k > i) v[4 * j + k] = 0.f;
    }

    float mx = v[0];
#pragma unroll
    for (int t = 1; t < 32; ++t) mx = fmaxf(mx, v[t]);
#pragma unroll
    for (int off = 32; off; off >>= 1) mx = fmaxf(mx, __shfl_xor(mx, off));

    float s = 0.f;
#pragma unroll
    for (int t = 0; t < 32; ++t) { v[t] = __expf(v[t] - mx); s += v[t]; }
#pragma unroll
    for (int off = 32; off; off >>= 1) s += __shfl_xor(s, off);
    const float inv = 1.f / s;

    short* orow = NW + (size_t)row * LL;
#pragma unroll
    for (int j = 0; j < 8; ++j) {
        s4v o = { f2bf(v[4 * j + 0] * inv), f2bf(v[4 * j + 1] * inv),
                  f2bf(v[4 * j + 2] * inv), f2bf(v[4 * j + 3] * inv) };
        *(s4v*)(orow + (j * 64 + lane) * 4) = o;
    }
}

// ---------------------------------------------------------------------------
// 2) transpose x (B,L,H,hd) f32 -> xT[h][b*64+d][l] bf16   (K-major B^T)
// grid (L/32, HD/32, H*B), block (32,8)
// ---------------------------------------------------------------------------
__global__ __launch_bounds__(256) void transpose_x(const float* __restrict__ x,
                                                   short* __restrict__ xT) {
    const int hb = blockIdx.z;
    const int h = hb >> 3, b = hb & 7;
    const int l0 = blockIdx.x * 32, d0 = blockIdx.y * 32;
    const int tx = threadIdx.x, ty = threadIdx.y;

    __shared__ float tile[32][33];
#pragma unroll
    for (int j = 0; j < 4; ++j) {
        int l = l0 + ty + 8 * j;
        tile[ty + 8 * j][tx] = x[((size_t)(b * LL + l)) * DD + h * HD + d0 + tx];
    }
    __syncthreads();
#pragma unroll
    for (int j = 0; j < 4; ++j) {
        int n = b * HD + d0 + ty + 8 * j;
        xT[((size_t)(h * NMIX + n)) * LL + l0 + tx] = f2bf(tile[tx][ty + 8 * j]);
    }
}

// ---------------------------------------------------------------------------
// 3) W_proj f32 -> bf16 (layout already B^T: row j, col k)
// ---------------------------------------------------------------------------
__global__ __launch_bounds__(256) void cvt_wproj(const float* __restrict__ Wp,
                                                 short* __restrict__ WpB) {
    const int idx = (blockIdx.x * 256 + threadIdx.x) * 4;
    float4 v = *(const float4*)&Wp[idx];
    s4v o = { f2bf(v.x), f2bf(v.y), f2bf(v.z), f2bf(v.w) };
    *(s4v*)&WpB[idx] = o;
}

// ---------------------------------------------------------------------------
// 4) mixing GEMM (per head): C[i][n] = sum_l NW_h[i][l] * xT_h[n][l]
//    M=2048 N=512 K=2048, m97 structure + T1 XCD swizzle (1024 blocks, %8==0)
//    epilogue: mixed[(b*2048+i)*1024 + h*64 + d] bf16, where n = b*64+d
// ---------------------------------------------------------------------------
__global__ __launch_bounds__(256) void gemm_mix(const short* __restrict__ NW,
                                                const short* __restrict__ xT,
                                                short* __restrict__ mixed) {
    constexpr int K = LL;
    // T1: bijective XCD swizzle over the flat 1024-block grid
    const u32 flat = blockIdx.x + 16u * (blockIdx.y + 4u * blockIdx.z);
    const u32 swz = (flat & 7u) * 128u + (flat >> 3);
    const int rb = (int)(swz & 15u);        // row block 0..15
    const int cb = (int)((swz >> 4) & 3u);  // col block 0..3
    const int h  = (int)(swz >> 6);         // head 0..15
    const short* A  = NW + (size_t)h * LL * LL;
    const short* BT = xT + (size_t)h * NMIX * LL;
    const int row0 = rb * 128;
    const int col0 = cb * 128;

    __shared__ short sA[128 * 32];
    __shared__ short sB[128 * 32];

    const int tid = threadIdx.x;
    const int wave = tid >> 6, lane = tid & 63;
    const int fr = lane & 15, fq = lane >> 4;
    const int wr = wave >> 1, wc = wave & 1;
    const int srow = lane >> 2;          // 0..15 row within 16-row segment
    const int scol = (lane & 3) * 8;     // element offset (8 bf16 = 16 B)

    f32x4 acc[4][4];
#pragma unroll
    for (int m = 0; m < 4; ++m)
#pragma unroll
        for (int n = 0; n < 4; ++n)
            acc[m][n] = f32x4{0.f, 0.f, 0.f, 0.f};

    for (int k0 = 0; k0 < K; k0 += 32) {
#pragma unroll
        for (int q = 0; q < 2; ++q) {
            const int sseg = q * 4 + wave;
            const short* ga = A  + (size_t)(row0 + sseg * 16 + srow) * K + k0 + scol;
            const short* gb = BT + (size_t)(col0 + sseg * 16 + srow) * K + k0 + scol;
            gload16(ga, &sA[sseg * 512]);
            gload16(gb, &sB[sseg * 512]);
        }
        __syncthreads();
        bf16x8 af[4], bfv[4];
#pragma unroll
        for (int m = 0; m < 4; ++m)
            af[m] = *(const bf16x8*)&sA[(wr * 64 + m * 16 + fr) * 32 + fq * 8];
#pragma unroll
        for (int n = 0; n < 4; ++n)
            bfv[n] = *(const bf16x8*)&sB[(wc * 64 + n * 16 + fr) * 32 + fq * 8];
#pragma unroll
        for (int m = 0; m < 4; ++m)
#pragma unroll
            for (int n = 0; n < 4; ++n)
                acc[m][n] = __builtin_amdgcn_mfma_f32_16x16x32_bf16(af[m], bfv[n], acc[m][n], 0, 0, 0);
        __syncthreads();
    }

    const int hbase = h * HD;
#pragma unroll
    for (int m = 0; m < 4; ++m) {
        const int gi = row0 + wr * 64 + m * 16 + fq * 4;   // position i (0..2047)
#pragma unroll
        for (int n = 0; n < 4; ++n) {
            const int ng = col0 + wc * 64 + n * 16 + fr;   // n = b*64+d
            const int bb = ng >> 6, dd = ng & 63;
            const size_t base = ((size_t)(bb * LL) + gi) * DD + hbase + dd;
#pragma unroll
            for (int r = 0; r < 4; ++r)
                mixed[base + (size_t)r * DD] = f2bf(acc[m][n][r]);
        }
    }
}

// ---------------------------------------------------------------------------
// 5) projection GEMM: out[m][j] = sum_k mixed[m][k] * WpB[j][k] + bias[j]
//    M=16384 N=1024 K=1024, m97 structure + T1 XCD swizzle (1024 blocks)
// ---------------------------------------------------------------------------
__global__ __launch_bounds__(256) void gemm_proj(const short* __restrict__ Amix,
                                                 const short* __restrict__ WpB,
                                                 const float* __restrict__ bias,
                                                 float* __restrict__ out) {
    constexpr int K = DD;
    // T1: bijective XCD swizzle over the flat 1024-block grid
    const u32 flat = blockIdx.x + 128u * blockIdx.y;
    const u32 swz = (flat & 7u) * 128u + (flat >> 3);
    const int row0 = (int)(swz & 127u) * 128;
    const int col0 = (int)(swz >> 7) * 128;

    __shared__ short sA[128 * 32];
    __shared__ short sB[128 * 32];

    const int tid = threadIdx.x;
    const int wave = tid >> 6, lane = tid & 63;
    const int fr = lane & 15, fq = lane >> 4;
    const int wr = wave >> 1, wc = wave & 1;
    const int srow = lane >> 2;
    const int scol = (lane & 3) * 8;

    f32x4 acc[4][4];
#pragma unroll
    for (int m = 0; m < 4; ++m)
#pragma unroll
        for (int n = 0; n < 4; ++n)
            acc[m][n] = f32x4{0.f, 0.f, 0.f, 0.f};

    for (int k0 = 0; k0 < K; k0 += 32) {
#pragma unroll
        for (int q = 0; q < 2; ++q) {
            const int sseg = q * 4 + wave;
            const short* ga = Amix + (size_t)(row0 + sseg * 16 + srow) * K + k0 + scol;
            const short* gb = WpB  + (size_t)(col0 + sseg * 16 + srow) * K + k0 + scol;
            gload16(ga, &sA[sseg * 512]);
            gload16(gb, &sB[sseg * 512]);
        }
        __syncthreads();
        bf16x8 af[4], bfv[4];
#pragma unroll
        for (int m = 0; m < 4; ++m)
            af[m] = *(const bf16x8*)&sA[(wr * 64 + m * 16 + fr) * 32 + fq * 8];
#pragma unroll
        for (int n = 0; n < 4; ++n)
            bfv[n] = *(const bf16x8*)&sB[(wc * 64 + n * 16 + fr) * 32 + fq * 8];
#pragma unroll
        for (int m = 0; m < 4; ++m)
#pragma unroll
            for (int n = 0; n < 4; ++n)
                acc[m][n] = __builtin_amdgcn_mfma_f32_16x16x32_bf16(af[m], bfv[n], acc[m][n], 0, 0, 0);
        __syncthreads();
    }

#pragma unroll
    for (int m = 0; m < 4; ++m) {
        const int grow = row0 + wr * 64 + m * 16 + fq * 4;
#pragma unroll
        for (int n = 0; n < 4; ++n) {
            const int gcol = col0 + wc * 64 + n * 16 + fr;
            const float bj = bias[gcol];
#pragma unroll
            for (int r = 0; r < 4; ++r)
                out[(size_t)(grow + r) * DD + gcol] = acc[m][n][r] + bj;
        }
    }
}

// ---------------------------------------------------------------------------
extern "C" void kernel_launch(void* const* d_in, const int* in_sizes, int n_in,
                              void* d_out, int out_size, void* d_ws, size_t ws_size,
                              hipStream_t stream) {
    const float* x  = (const float*)d_in[0];
    const float* W  = (const float*)d_in[1];
    const float* Wp = (const float*)d_in[2];
    const float* bp = (const float*)d_in[3];
    float* out = (float*)d_out;

    char* ws = (char*)d_ws;
    short* NW    = (short*)(ws);                       // 16*2048*2048*2 = 134217728 B
    short* xT    = (short*)(ws + 134217728);           // 16*512*2048*2  =  33554432 B
    short* mixed = (short*)(ws + 167772160);           // 16384*1024*2   =  33554432 B
    short* WpB   = (short*)(ws + 201326592);           // 1024*1024*2    =   2097152 B
    // total workspace use: 203423744 B (~194 MB)

    softmax_kernel<<<HH * LL / 4, 256, 0, stream>>>(W, NW);
    transpose_x<<<dim3(LL / 32, HD / 32, HH * BB), dim3(32, 8), 0, stream>>>(x, xT);
    cvt_wproj<<<1024, 256, 0, stream>>>(Wp, WpB);
    gemm_mix<<<dim3(LL / 128, NMIX / 128, HH), 256, 0, stream>>>(NW, xT, mixed);
    gemm_proj<<<dim3((BB * LL) / 128, DD / 128), 256, 0, stream>>>(mixed, WpB, bp, out);
}